// Round 4
// baseline (211.183 us; speedup 1.0000x reference)
//
#include <hip/hip_runtime.h>
#include <hip/hip_bf16.h>

// ---------------------------------------------------------------------------
// GlobalIntrinsicLinear: Fastfood update + GEMM
//   LL = 1<<20, DD = 1024*768, OUT=1024, IN=768, M = 8*2048 = 16384
// Inputs: x(8,2048,768) f32, theta(2048) f32, W_0(1024,768) f32, b(1024) f32,
//         BB(LL) f32, GG(LL) f32, Pi(LL) int32 (harness narrows int64)
// Output: (8,2048,1024) f32
//
// R4: GEMM: BK=64, kc-major LDS layout (conflict-free ds_read_b128),
//     m-fastest grid (A fetched once across XCDs). sum(GG^2) folded into
//     k3 (partials) + k4 block 0 (final reduce); k1 dispatch removed.
// ---------------------------------------------------------------------------

#define LL (1 << 20)
#define DD (1024 * 768)
#define OUTF 1024
#define INF 768
#define MROWS 16384

typedef __attribute__((ext_vector_type(8))) short s16x8;
typedef __attribute__((ext_vector_type(4))) float f32x4;

__device__ __forceinline__ unsigned short f2bf(float f) {
    union { float f; unsigned u; } v; v.f = f;
    unsigned r = v.u + 0x7FFF + ((v.u >> 16) & 1);   // RNE
    return (unsigned short)(r >> 16);
}

// ---------------------------------------------------------------------------
// K0: FWHT-1024 of the two nonzero rows of BB*theta_pad.
// One block, 256 threads. Writes r01[2048] = {r0, r1}.
// Math: FWHT_{2^20} of a vector nonzero only at q<2048 collapses to
//   v1[p] = r0[p&1023] + (-1)^{bit10(p)} * r1[p&1023].
// ---------------------------------------------------------------------------
__global__ void k0_fwht2(const float* __restrict__ BB, const float* __restrict__ theta,
                         float* __restrict__ r01) {
    __shared__ float s[2048];
    const int tid = threadIdx.x;
    for (int j = tid; j < 2048; j += 256) s[j] = BB[j] * theta[j];
    for (int h = 1; h < 1024; h <<= 1) {
        __syncthreads();
        for (int w = tid; w < 1024; w += 256) {
            int row = w >> 9;
            int b   = w & 511;
            int bh  = b & (h - 1);
            int i   = ((b - bh) << 1) + bh + row * 1024;
            float a = s[i], c = s[i + h];
            s[i] = a + c; s[i + h] = a - c;
        }
    }
    __syncthreads();
    for (int j = tid; j < 2048; j += 256) r01[j] = s[j];
}

// ---------------------------------------------------------------------------
// K3: fused gather + FWHT-1024 along low-10 bits + sum(GG^2) block partials.
// One row (hi index) per block. t[i] = (r0[lo] + sgn*r1[lo]) * GG[i].
// ---------------------------------------------------------------------------
__global__ void k3_gather_fwht_lo(const int* __restrict__ Pi, const float* __restrict__ GG,
                                  const float* __restrict__ r01, float* __restrict__ T,
                                  float* __restrict__ partial) {
    __shared__ float s[1024];
    __shared__ float r01s[2048];
    __shared__ float ws4[4];
    const int tid = threadIdx.x;
    const int row = blockIdx.x;
    for (int j = tid; j < 2048; j += 256) r01s[j] = r01[j];
    const int4   pv = ((const int4*)Pi)[row * 256 + tid];
    const float4 gv = ((const float4*)GG)[row * 256 + tid];
    // sum(GG^2) partial for this block (no atomics)
    float g2 = gv.x * gv.x + gv.y * gv.y + gv.z * gv.z + gv.w * gv.w;
    #pragma unroll
    for (int o = 32; o > 0; o >>= 1) g2 += __shfl_down(g2, o, 64);
    if ((tid & 63) == 0) ws4[tid >> 6] = g2;
    __syncthreads();
    {
        int p; float g, v;
        p = pv.x; g = gv.x;
        v = (r01s[p & 1023] + (((p >> 10) & 1) ? -1.0f : 1.0f) * r01s[1024 + (p & 1023)]) * g;
        s[tid * 4 + 0] = v;
        p = pv.y; g = gv.y;
        v = (r01s[p & 1023] + (((p >> 10) & 1) ? -1.0f : 1.0f) * r01s[1024 + (p & 1023)]) * g;
        s[tid * 4 + 1] = v;
        p = pv.z; g = gv.z;
        v = (r01s[p & 1023] + (((p >> 10) & 1) ? -1.0f : 1.0f) * r01s[1024 + (p & 1023)]) * g;
        s[tid * 4 + 2] = v;
        p = pv.w; g = gv.w;
        v = (r01s[p & 1023] + (((p >> 10) & 1) ? -1.0f : 1.0f) * r01s[1024 + (p & 1023)]) * g;
        s[tid * 4 + 3] = v;
    }
    for (int h = 1; h < 1024; h <<= 1) {
        __syncthreads();
        for (int w = tid; w < 512; w += 256) {
            int bh = w & (h - 1);
            int i  = ((w - bh) << 1) + bh;
            float a = s[i], c = s[i + h];
            s[i] = a + c; s[i + h] = a - c;
        }
    }
    __syncthreads();
    float4 v;
    v.x = s[tid * 4 + 0]; v.y = s[tid * 4 + 1]; v.z = s[tid * 4 + 2]; v.w = s[tid * 4 + 3];
    ((float4*)T)[row * 256 + tid] = v;
    if (tid == 0) partial[row] = ws4[0] + ws4[1] + ws4[2] + ws4[3];
}

// ---------------------------------------------------------------------------
// K4: FWHT-1024 along the high-10 bits. 128 blocks x 8 lo-columns each.
// LDS tile [8][1025] = 32.8 KB (pad +1 -> conflict-free butterflies).
// Block 0 additionally reduces the 1024 sum(GG^2) partials -> S.
// ---------------------------------------------------------------------------
__global__ void k4_fwht_hi(float* __restrict__ T, const float* __restrict__ partial,
                           float* __restrict__ S) {
    __shared__ float s[8 * 1025];
    __shared__ float rw[4];
    const int tid = threadIdx.x;
    if (blockIdx.x == 0) {
        float p = partial[tid] + partial[tid + 256] + partial[tid + 512] + partial[tid + 768];
        #pragma unroll
        for (int o = 32; o > 0; o >>= 1) p += __shfl_down(p, o, 64);
        if ((tid & 63) == 0) rw[tid >> 6] = p;
        __syncthreads();
        if (tid == 0) *S = rw[0] + rw[1] + rw[2] + rw[3];
    }
    const int lo0 = blockIdx.x * 8;
    float4* T4 = (float4*)T;
    const int hio = tid >> 1;     // 0..127
    const int q   = tid & 1;      // which float4 of the 8 columns
    for (int hb = 0; hb < 8; hb++) {
        int hi = hb * 128 + hio;
        float4 v = T4[hi * 256 + (lo0 >> 2) + q];
        s[(4 * q + 0) * 1025 + hi] = v.x;
        s[(4 * q + 1) * 1025 + hi] = v.y;
        s[(4 * q + 2) * 1025 + hi] = v.z;
        s[(4 * q + 3) * 1025 + hi] = v.w;
    }
    for (int h = 1; h < 1024; h <<= 1) {
        __syncthreads();
        for (int w = tid; w < 8 * 512; w += 256) {
            int col = w >> 9;
            int b   = w & 511;
            int bh  = b & (h - 1);
            int i   = ((b - bh) << 1) + bh;
            float* p = s + col * 1025;
            float a = p[i], c = p[i + h];
            p[i] = a + c; p[i + h] = a - c;
        }
    }
    __syncthreads();
    for (int hb = 0; hb < 8; hb++) {
        int hi = hb * 128 + hio;
        float4 v;
        v.x = s[(4 * q + 0) * 1025 + hi];
        v.y = s[(4 * q + 1) * 1025 + hi];
        v.z = s[(4 * q + 2) * 1025 + hi];
        v.w = s[(4 * q + 3) * 1025 + hi];
        T4[hi * 256 + (lo0 >> 2) + q] = v;
    }
}

// ---------------------------------------------------------------------------
// K5: W_eff = bf16(W_0 + v[:DD] * rsqrt(S*DD))   (row-major 1024x768)
// ---------------------------------------------------------------------------
__global__ void k5_weff(const float* __restrict__ T, const float* __restrict__ W0,
                        const float* __restrict__ S, ushort* __restrict__ WB) {
    const int i = blockIdx.x * 256 + threadIdx.x;     // float4 index, DD/4 total
    const float scale = rsqrtf(*S * (float)DD);
    float4 v = ((const float4*)T)[i];
    float4 w = ((const float4*)W0)[i];
    ushort4 o;
    o.x = f2bf(w.x + v.x * scale);
    o.y = f2bf(w.y + v.y * scale);
    o.z = f2bf(w.z + v.z * scale);
    o.w = f2bf(w.w + v.w * scale);
    ((ushort4*)WB)[i] = o;
}

// ---------------------------------------------------------------------------
// K6: x (f32) -> bf16
// ---------------------------------------------------------------------------
__global__ void k6_xcast(const float* __restrict__ X, ushort* __restrict__ XB) {
    const int i = blockIdx.x * 256 + threadIdx.x;     // float4 index
    float4 v = ((const float4*)X)[i];
    ushort4 o;
    o.x = f2bf(v.x); o.y = f2bf(v.y); o.z = f2bf(v.z); o.w = f2bf(v.w);
    ((ushort4*)XB)[i] = o;
}

// ---------------------------------------------------------------------------
// K7: GEMM  C[m][n] = sum_k A[m][k]*B[n][k] + bias[n]
// A: MROWS x 768 bf16, B: 1024 x 768 bf16 (W_eff), C: f32.
// 128x128 tile, BK=64, 4 waves (2x2), each wave 4x4 MFMA 16x16x32 tiles x2 k-steps.
// kc-major LDS layout: segment s -> row = s&127, kc = s>>7, LDS off = s*16B.
//   -> fragment ds_read_b128 is phase-contiguous (conflict-free).
// Grid: x = m-tile (fast) so consecutive blocks read disjoint A (XCD L2).
// ---------------------------------------------------------------------------
#define BM 128
#define BN 128
#define BK 64

__global__ __launch_bounds__(256)
void k7_gemm(const ushort* __restrict__ A, const ushort* __restrict__ B,
             const float* __restrict__ bias, float* __restrict__ C) {
    __shared__ ushort As[BM * BK];   // 16 KB
    __shared__ ushort Bs[BN * BK];   // 16 KB
    const int tid  = threadIdx.x;
    const int lane = tid & 63;
    const int wave = tid >> 6;
    const int m0 = blockIdx.x * BM;
    const int n0 = blockIdx.y * BN;
    const int wm = (wave & 1) * 64;
    const int wn = (wave >> 1) * 64;

    const int fr_row = lane & 15;
    const int fr_kg  = lane >> 4;     // k-group 0..3 (8 k each)

    f32x4 acc[4][4];
    #pragma unroll
    for (int i = 0; i < 4; i++)
        #pragma unroll
        for (int j = 0; j < 4; j++) acc[i][j] = (f32x4)(0.0f);

    for (int kt = 0; kt < INF; kt += BK) {
        // --- stage A and B tiles: 1024 segments x 16B each, 4 issues each ---
        #pragma unroll
        for (int i = 0; i < 4; i++) {
            const int s   = i * 256 + tid;
            const int row = s & 127;
            const int kc  = s >> 7;
            const ushort* ga = A + (size_t)(m0 + row) * INF + kt + kc * 8;
            const ushort* gb = B + (size_t)(n0 + row) * INF + kt + kc * 8;
            __builtin_amdgcn_global_load_lds(
                (const __attribute__((address_space(1))) void*)ga,
                (__attribute__((address_space(3))) void*)&As[i * 2048 + wave * 512], 16, 0, 0);
            __builtin_amdgcn_global_load_lds(
                (const __attribute__((address_space(1))) void*)gb,
                (__attribute__((address_space(3))) void*)&Bs[i * 2048 + wave * 512], 16, 0, 0);
        }
        __syncthreads();

        // --- fragments + MFMA, two 32-k steps ---
        #pragma unroll
        for (int ks = 0; ks < 2; ks++) {
            const int kc = ks * 4 + fr_kg;
            s16x8 af[4], bf[4];
            #pragma unroll
            for (int mi = 0; mi < 4; mi++)
                af[mi] = *(const s16x8*)&As[(kc * 128 + wm + mi * 16 + fr_row) * 8];
            #pragma unroll
            for (int ni = 0; ni < 4; ni++)
                bf[ni] = *(const s16x8*)&Bs[(kc * 128 + wn + ni * 16 + fr_row) * 8];
            #pragma unroll
            for (int mi = 0; mi < 4; mi++)
                #pragma unroll
                for (int ni = 0; ni < 4; ni++)
                    acc[mi][ni] = __builtin_amdgcn_mfma_f32_16x16x32_bf16(
                        af[mi], bf[ni], acc[mi][ni], 0, 0, 0);
        }
        __syncthreads();
    }

    // --- epilogue: C/D layout col=lane&15, row=(lane>>4)*4+reg ---
    const int crow = (lane >> 4) * 4;
    const int ccol = lane & 15;
    #pragma unroll
    for (int ni = 0; ni < 4; ni++) {
        const int n = n0 + wn + ni * 16 + ccol;
        const float bv = bias[n];
        #pragma unroll
        for (int mi = 0; mi < 4; mi++) {
            const int mbase = m0 + wm + mi * 16 + crow;
            #pragma unroll
            for (int r = 0; r < 4; r++)
                C[(size_t)(mbase + r) * OUTF + n] = acc[mi][ni][r] + bv;
        }
    }
}

// ---------------------------------------------------------------------------
extern "C" void kernel_launch(void* const* d_in, const int* in_sizes, int n_in,
                              void* d_out, int out_size, void* d_ws, size_t ws_size,
                              hipStream_t stream) {
    (void)in_sizes; (void)n_in; (void)out_size; (void)ws_size;
    const float* x     = (const float*)d_in[0];
    const float* theta = (const float*)d_in[1];
    const float* W0    = (const float*)d_in[2];
    const float* bias  = (const float*)d_in[3];
    const float* BB    = (const float*)d_in[4];
    const float* GG    = (const float*)d_in[5];
    const int*   Pi    = (const int*)d_in[6];      // int64 inputs arrive as int32
    float* out = (float*)d_out;

    char* ws = (char*)d_ws;
    ushort* XB   = (ushort*)ws;                      // 16384*768 bf16 = 25165824 B
    float*  T    = (float*)(ws + 25165824);          // LL f32 = 4194304 B
    ushort* WB   = (ushort*)(ws + 29360128);         // 1024*768 bf16 = 1572864 B
    float*  R01  = (float*)(ws + 30932992);          // 2048 f32
    float*  S    = (float*)(ws + 30941184);          // 1 f32
    float*  PART = (float*)(ws + 30941248);          // 1024 f32 partials

    k0_fwht2 <<<1,   256, 0, stream>>>(BB, theta, R01);
    k3_gather_fwht_lo<<<1024, 256, 0, stream>>>(Pi, GG, R01, T, PART);
    k4_fwht_hi<<<128, 256, 0, stream>>>(T, PART, S);
    k5_weff  <<<DD/1024, 256, 0, stream>>>(T, W0, S, WB);
    k6_xcast <<<(MROWS*INF)/1024, 256, 0, stream>>>(x, XB);
    k7_gemm  <<<dim3(MROWS/BM, OUTF/BN), 256, 0, stream>>>(XB, WB, bias, out);
}

// Round 5
// 185.521 us; speedup vs baseline: 1.1383x; 1.1383x over previous
//
#include <hip/hip_runtime.h>
#include <hip/hip_bf16.h>

// ---------------------------------------------------------------------------
// GlobalIntrinsicLinear: Fastfood update + GEMM
//   LL = 1<<20, DD = 1024*768, OUT=1024, IN=768, M = 8*2048 = 16384
// Inputs: x(8,2048,768) f32, theta(2048) f32, W_0(1024,768) f32, b(1024) f32,
//         BB(LL) f32, GG(LL) f32, Pi(LL) int32 (harness narrows int64)
// Output: (8,2048,1024) f32
//
// R5: GEMM LDS XOR-swizzle: slot s <-> (row=s>>3, kc=(s&7)^(row&7)).
//     -> staging: 8 lanes cover 128 B contiguous global (full coalescing)
//     -> ds_read_b128: 2-way bank aliasing only (free per m136).
//     (R4's kc-major mapping had conflict-free LDS but 16B-scattered global
//      loads -> k7 58->76us regression. XOR swizzle gives both.)
//     k0 fused into k3 (per-block r01 recompute in LDS).
// ---------------------------------------------------------------------------

#define LL (1 << 20)
#define DD (1024 * 768)
#define OUTF 1024
#define INF 768
#define MROWS 16384

typedef __attribute__((ext_vector_type(8))) short s16x8;
typedef __attribute__((ext_vector_type(4))) float f32x4;

__device__ __forceinline__ unsigned short f2bf(float f) {
    union { float f; unsigned u; } v; v.f = f;
    unsigned r = v.u + 0x7FFF + ((v.u >> 16) & 1);   // RNE
    return (unsigned short)(r >> 16);
}

// ---------------------------------------------------------------------------
// K3: fused {FWHT-1024 of the two nonzero rows of BB*theta_pad} + gather +
// FWHT-1024 along low-10 bits + sum(GG^2) block partials.
// One row (hi index) per block; r01 recomputed per block in LDS (BB/theta are
// 8 KB, broadcast across blocks -> L2 hits; ~10 extra LDS rounds, no k0 dispatch).
// Math: FWHT_{2^20} of a vector nonzero only at q<2048 collapses to
//   v1[p] = r0[p&1023] + (-1)^{bit10(p)} * r1[p&1023],  r0/r1 = FWHT_1024 rows.
// ---------------------------------------------------------------------------
__global__ void k3_gather_fwht_lo(const int* __restrict__ Pi, const float* __restrict__ GG,
                                  const float* __restrict__ BB, const float* __restrict__ theta,
                                  float* __restrict__ T, float* __restrict__ partial) {
    __shared__ float s[1024];
    __shared__ float r01s[2048];
    __shared__ float ws4[4];
    const int tid = threadIdx.x;
    const int row = blockIdx.x;
    // issue gather operands early (latency hidden behind r01 butterflies)
    const int4   pv = ((const int4*)Pi)[row * 256 + tid];
    const float4 gv = ((const float4*)GG)[row * 256 + tid];
    for (int j = tid; j < 2048; j += 256) r01s[j] = BB[j] * theta[j];
    for (int h = 1; h < 1024; h <<= 1) {
        __syncthreads();
        for (int w = tid; w < 1024; w += 256) {
            int rr = w >> 9;
            int b  = w & 511;
            int bh = b & (h - 1);
            int i  = ((b - bh) << 1) + bh + rr * 1024;
            float a = r01s[i], c = r01s[i + h];
            r01s[i] = a + c; r01s[i + h] = a - c;
        }
    }
    // sum(GG^2) partial for this block (no atomics)
    float g2 = gv.x * gv.x + gv.y * gv.y + gv.z * gv.z + gv.w * gv.w;
    #pragma unroll
    for (int o = 32; o > 0; o >>= 1) g2 += __shfl_down(g2, o, 64);
    if ((tid & 63) == 0) ws4[tid >> 6] = g2;
    __syncthreads();
    {
        int p; float g, v;
        p = pv.x; g = gv.x;
        v = (r01s[p & 1023] + (((p >> 10) & 1) ? -1.0f : 1.0f) * r01s[1024 + (p & 1023)]) * g;
        s[tid * 4 + 0] = v;
        p = pv.y; g = gv.y;
        v = (r01s[p & 1023] + (((p >> 10) & 1) ? -1.0f : 1.0f) * r01s[1024 + (p & 1023)]) * g;
        s[tid * 4 + 1] = v;
        p = pv.z; g = gv.z;
        v = (r01s[p & 1023] + (((p >> 10) & 1) ? -1.0f : 1.0f) * r01s[1024 + (p & 1023)]) * g;
        s[tid * 4 + 2] = v;
        p = pv.w; g = gv.w;
        v = (r01s[p & 1023] + (((p >> 10) & 1) ? -1.0f : 1.0f) * r01s[1024 + (p & 1023)]) * g;
        s[tid * 4 + 3] = v;
    }
    for (int h = 1; h < 1024; h <<= 1) {
        __syncthreads();
        for (int w = tid; w < 512; w += 256) {
            int bh = w & (h - 1);
            int i  = ((w - bh) << 1) + bh;
            float a = s[i], c = s[i + h];
            s[i] = a + c; s[i + h] = a - c;
        }
    }
    __syncthreads();
    float4 v;
    v.x = s[tid * 4 + 0]; v.y = s[tid * 4 + 1]; v.z = s[tid * 4 + 2]; v.w = s[tid * 4 + 3];
    ((float4*)T)[row * 256 + tid] = v;
    if (tid == 0) partial[row] = ws4[0] + ws4[1] + ws4[2] + ws4[3];
}

// ---------------------------------------------------------------------------
// K4: FWHT-1024 along the high-10 bits. 128 blocks x 8 lo-columns each.
// LDS tile [8][1025] = 32.8 KB (pad +1 -> conflict-free butterflies).
// Block 0 additionally reduces the 1024 sum(GG^2) partials -> S.
// ---------------------------------------------------------------------------
__global__ void k4_fwht_hi(float* __restrict__ T, const float* __restrict__ partial,
                           float* __restrict__ S) {
    __shared__ float s[8 * 1025];
    __shared__ float rw[4];
    const int tid = threadIdx.x;
    if (blockIdx.x == 0) {
        float p = partial[tid] + partial[tid + 256] + partial[tid + 512] + partial[tid + 768];
        #pragma unroll
        for (int o = 32; o > 0; o >>= 1) p += __shfl_down(p, o, 64);
        if ((tid & 63) == 0) rw[tid >> 6] = p;
        __syncthreads();
        if (tid == 0) *S = rw[0] + rw[1] + rw[2] + rw[3];
    }
    const int lo0 = blockIdx.x * 8;
    float4* T4 = (float4*)T;
    const int hio = tid >> 1;     // 0..127
    const int q   = tid & 1;      // which float4 of the 8 columns
    for (int hb = 0; hb < 8; hb++) {
        int hi = hb * 128 + hio;
        float4 v = T4[hi * 256 + (lo0 >> 2) + q];
        s[(4 * q + 0) * 1025 + hi] = v.x;
        s[(4 * q + 1) * 1025 + hi] = v.y;
        s[(4 * q + 2) * 1025 + hi] = v.z;
        s[(4 * q + 3) * 1025 + hi] = v.w;
    }
    for (int h = 1; h < 1024; h <<= 1) {
        __syncthreads();
        for (int w = tid; w < 8 * 512; w += 256) {
            int col = w >> 9;
            int b   = w & 511;
            int bh  = b & (h - 1);
            int i   = ((b - bh) << 1) + bh;
            float* p = s + col * 1025;
            float a = p[i], c = p[i + h];
            p[i] = a + c; p[i + h] = a - c;
        }
    }
    __syncthreads();
    for (int hb = 0; hb < 8; hb++) {
        int hi = hb * 128 + hio;
        float4 v;
        v.x = s[(4 * q + 0) * 1025 + hi];
        v.y = s[(4 * q + 1) * 1025 + hi];
        v.z = s[(4 * q + 2) * 1025 + hi];
        v.w = s[(4 * q + 3) * 1025 + hi];
        T4[hi * 256 + (lo0 >> 2) + q] = v;
    }
}

// ---------------------------------------------------------------------------
// K5: W_eff = bf16(W_0 + v[:DD] * rsqrt(S*DD))   (row-major 1024x768)
// ---------------------------------------------------------------------------
__global__ void k5_weff(const float* __restrict__ T, const float* __restrict__ W0,
                        const float* __restrict__ S, ushort* __restrict__ WB) {
    const int i = blockIdx.x * 256 + threadIdx.x;     // float4 index, DD/4 total
    const float scale = rsqrtf(*S * (float)DD);
    float4 v = ((const float4*)T)[i];
    float4 w = ((const float4*)W0)[i];
    ushort4 o;
    o.x = f2bf(w.x + v.x * scale);
    o.y = f2bf(w.y + v.y * scale);
    o.z = f2bf(w.z + v.z * scale);
    o.w = f2bf(w.w + v.w * scale);
    ((ushort4*)WB)[i] = o;
}

// ---------------------------------------------------------------------------
// K6: x (f32) -> bf16
// ---------------------------------------------------------------------------
__global__ void k6_xcast(const float* __restrict__ X, ushort* __restrict__ XB) {
    const int i = blockIdx.x * 256 + threadIdx.x;     // float4 index
    float4 v = ((const float4*)X)[i];
    ushort4 o;
    o.x = f2bf(v.x); o.y = f2bf(v.y); o.z = f2bf(v.z); o.w = f2bf(v.w);
    ((ushort4*)XB)[i] = o;
}

// ---------------------------------------------------------------------------
// K7: GEMM  C[m][n] = sum_k A[m][k]*B[n][k] + bias[n]
// A: MROWS x 768 bf16, B: 1024 x 768 bf16 (W_eff), C: f32.
// 128x128 tile, BK=64, 4 waves (2x2), each wave 4x4 MFMA 16x16x32 x2 k-steps.
// XOR-swizzled LDS: 16B slot s <-> row = s>>3, kc = (s&7) ^ (row&7).
//   staging: lanes 8-at-a-time cover 128 B contiguous global memory;
//   fragment ds_read_b128: slot%8 hits each value 2x per 16-lane phase
//   (2-way aliasing = free). Grid: x = m-tile (disjoint A per XCD).
// ---------------------------------------------------------------------------
#define BM 128
#define BN 128
#define BK 64

__global__ __launch_bounds__(256)
void k7_gemm(const ushort* __restrict__ A, const ushort* __restrict__ B,
             const float* __restrict__ bias, float* __restrict__ C) {
    __shared__ ushort As[BM * BK];   // 16 KB
    __shared__ ushort Bs[BN * BK];   // 16 KB
    const int tid  = threadIdx.x;
    const int lane = tid & 63;
    const int wave = tid >> 6;
    const int m0 = blockIdx.x * BM;
    const int n0 = blockIdx.y * BN;
    const int wm = (wave & 1) * 64;
    const int wn = (wave >> 1) * 64;

    const int fr_row = lane & 15;
    const int fr_kg  = lane >> 4;     // k-group 0..3 (8 k each)

    f32x4 acc[4][4];
    #pragma unroll
    for (int i = 0; i < 4; i++)
        #pragma unroll
        for (int j = 0; j < 4; j++) acc[i][j] = (f32x4)(0.0f);

    for (int kt = 0; kt < INF; kt += BK) {
        // --- stage A/B tiles: 1024 slots x 16B each; XOR-swizzled mapping ---
        #pragma unroll
        for (int i = 0; i < 4; i++) {
            const int s   = i * 256 + tid;       // LDS slot (16B units)
            const int row = s >> 3;
            const int kc  = (s & 7) ^ (row & 7);
            const ushort* ga = A + (size_t)(m0 + row) * INF + kt + kc * 8;
            const ushort* gb = B + (size_t)(n0 + row) * INF + kt + kc * 8;
            __builtin_amdgcn_global_load_lds(
                (const __attribute__((address_space(1))) void*)ga,
                (__attribute__((address_space(3))) void*)&As[i * 2048 + wave * 512], 16, 0, 0);
            __builtin_amdgcn_global_load_lds(
                (const __attribute__((address_space(1))) void*)gb,
                (__attribute__((address_space(3))) void*)&Bs[i * 2048 + wave * 512], 16, 0, 0);
        }
        __syncthreads();

        // --- fragments + MFMA, two 32-k steps ---
        #pragma unroll
        for (int ks = 0; ks < 2; ks++) {
            const int kc = ks * 4 + fr_kg;
            s16x8 af[4], bf[4];
            #pragma unroll
            for (int mi = 0; mi < 4; mi++) {
                const int r = wm + mi * 16 + fr_row;
                af[mi] = *(const s16x8*)&As[(r * 8 + (kc ^ (r & 7))) * 8];
            }
            #pragma unroll
            for (int ni = 0; ni < 4; ni++) {
                const int r = wn + ni * 16 + fr_row;
                bf[ni] = *(const s16x8*)&Bs[(r * 8 + (kc ^ (r & 7))) * 8];
            }
            #pragma unroll
            for (int mi = 0; mi < 4; mi++)
                #pragma unroll
                for (int ni = 0; ni < 4; ni++)
                    acc[mi][ni] = __builtin_amdgcn_mfma_f32_16x16x32_bf16(
                        af[mi], bf[ni], acc[mi][ni], 0, 0, 0);
        }
        __syncthreads();
    }

    // --- epilogue: C/D layout col=lane&15, row=(lane>>4)*4+reg ---
    const int crow = (lane >> 4) * 4;
    const int ccol = lane & 15;
    #pragma unroll
    for (int ni = 0; ni < 4; ni++) {
        const int n = n0 + wn + ni * 16 + ccol;
        const float bv = bias[n];
        #pragma unroll
        for (int mi = 0; mi < 4; mi++) {
            const int mbase = m0 + wm + mi * 16 + crow;
            #pragma unroll
            for (int r = 0; r < 4; r++)
                C[(size_t)(mbase + r) * OUTF + n] = acc[mi][ni][r] + bv;
        }
    }
}

// ---------------------------------------------------------------------------
extern "C" void kernel_launch(void* const* d_in, const int* in_sizes, int n_in,
                              void* d_out, int out_size, void* d_ws, size_t ws_size,
                              hipStream_t stream) {
    (void)in_sizes; (void)n_in; (void)out_size; (void)ws_size;
    const float* x     = (const float*)d_in[0];
    const float* theta = (const float*)d_in[1];
    const float* W0    = (const float*)d_in[2];
    const float* bias  = (const float*)d_in[3];
    const float* BB    = (const float*)d_in[4];
    const float* GG    = (const float*)d_in[5];
    const int*   Pi    = (const int*)d_in[6];      // int64 inputs arrive as int32
    float* out = (float*)d_out;

    char* ws = (char*)d_ws;
    ushort* XB   = (ushort*)ws;                      // 16384*768 bf16 = 25165824 B
    float*  T    = (float*)(ws + 25165824);          // LL f32 = 4194304 B
    ushort* WB   = (ushort*)(ws + 29360128);         // 1024*768 bf16 = 1572864 B
    float*  S    = (float*)(ws + 30932992);          // 1 f32
    float*  PART = (float*)(ws + 30933056);          // 1024 f32 partials

    k3_gather_fwht_lo<<<1024, 256, 0, stream>>>(Pi, GG, BB, theta, T, PART);
    k4_fwht_hi<<<128, 256, 0, stream>>>(T, PART, S);
    k5_weff  <<<DD/1024, 256, 0, stream>>>(T, W0, S, WB);
    k6_xcast <<<(MROWS*INF)/1024, 256, 0, stream>>>(x, XB);
    k7_gemm  <<<dim3(MROWS/BM, OUTF/BN), 256, 0, stream>>>(XB, WB, bias, out);
}

// Round 6
// 180.571 us; speedup vs baseline: 1.1695x; 1.0274x over previous
//
#include <hip/hip_runtime.h>
#include <hip/hip_bf16.h>

// ---------------------------------------------------------------------------
// GlobalIntrinsicLinear: Fastfood update + GEMM
//   LL = 1<<20, DD = 1024*768, OUT=1024, IN=768, M = 8*2048 = 16384
// Inputs: x(8,2048,768) f32, theta(2048) f32, W_0(1024,768) f32, b(1024) f32,
//         BB(LL) f32, GG(LL) f32, Pi(LL) int32 (harness narrows int64)
// Output: (8,2048,1024) f32
//
// R6: pipeline compressed to 3 dispatches:
//   k3: r01-FWHT + gather + lo-FWHT + GG^2 partials + x f32->bf16 cast tail
//       (k6 deleted; cast overlaps k3's barrier-bound FWHT phase)
//   k4: hi-FWHT + per-block redundant S reduction + W_eff bf16 write
//       (k5 deleted; T write-back dropped)
//   k7: unchanged R5 GEMM (XOR-swizzled LDS, 0 conflicts, FETCH 31 MB)
// ---------------------------------------------------------------------------

#define LL (1 << 20)
#define DD (1024 * 768)
#define OUTF 1024
#define INF 768
#define MROWS 16384

typedef __attribute__((ext_vector_type(8))) short s16x8;
typedef __attribute__((ext_vector_type(4))) float f32x4;

__device__ __forceinline__ unsigned short f2bf(float f) {
    union { float f; unsigned u; } v; v.f = f;
    unsigned r = v.u + 0x7FFF + ((v.u >> 16) & 1);   // RNE
    return (unsigned short)(r >> 16);
}

// ---------------------------------------------------------------------------
// K3: fused {FWHT-1024 of the two nonzero rows of BB*theta_pad} + gather +
// FWHT-1024 along low-10 bits + sum(GG^2) block partials + x-cast tail.
// One hi-row per block (1024 blocks).
// Math: FWHT_{2^20} of a vector nonzero only at q<2048 collapses to
//   v1[p] = r0[p&1023] + (-1)^{bit10(p)} * r1[p&1023],  r0/r1 = FWHT_1024 rows.
// ---------------------------------------------------------------------------
__global__ void k3_gather_fwht_lo(const int* __restrict__ Pi, const float* __restrict__ GG,
                                  const float* __restrict__ BB, const float* __restrict__ theta,
                                  const float* __restrict__ X, ushort* __restrict__ XB,
                                  float* __restrict__ T, float* __restrict__ partial) {
    __shared__ float s[1024];
    __shared__ float r01s[2048];
    __shared__ float ws4[4];
    const int tid = threadIdx.x;
    const int row = blockIdx.x;
    // gather operands early (latency hidden behind r01 butterflies)
    const int4   pv = ((const int4*)Pi)[row * 256 + tid];
    const float4 gv = ((const float4*)GG)[row * 256 + tid];
    for (int j = tid; j < 2048; j += 256) r01s[j] = BB[j] * theta[j];
    for (int h = 1; h < 1024; h <<= 1) {
        __syncthreads();
        for (int w = tid; w < 1024; w += 256) {
            int rr = w >> 9;
            int b  = w & 511;
            int bh = b & (h - 1);
            int i  = ((b - bh) << 1) + bh + rr * 1024;
            float a = r01s[i], c = r01s[i + h];
            r01s[i] = a + c; r01s[i + h] = a - c;
        }
    }
    // sum(GG^2) partial for this block (no atomics)
    float g2 = gv.x * gv.x + gv.y * gv.y + gv.z * gv.z + gv.w * gv.w;
    #pragma unroll
    for (int o = 32; o > 0; o >>= 1) g2 += __shfl_down(g2, o, 64);
    if ((tid & 63) == 0) ws4[tid >> 6] = g2;
    __syncthreads();
    {
        int p; float g, v;
        p = pv.x; g = gv.x;
        v = (r01s[p & 1023] + (((p >> 10) & 1) ? -1.0f : 1.0f) * r01s[1024 + (p & 1023)]) * g;
        s[tid * 4 + 0] = v;
        p = pv.y; g = gv.y;
        v = (r01s[p & 1023] + (((p >> 10) & 1) ? -1.0f : 1.0f) * r01s[1024 + (p & 1023)]) * g;
        s[tid * 4 + 1] = v;
        p = pv.z; g = gv.z;
        v = (r01s[p & 1023] + (((p >> 10) & 1) ? -1.0f : 1.0f) * r01s[1024 + (p & 1023)]) * g;
        s[tid * 4 + 2] = v;
        p = pv.w; g = gv.w;
        v = (r01s[p & 1023] + (((p >> 10) & 1) ? -1.0f : 1.0f) * r01s[1024 + (p & 1023)]) * g;
        s[tid * 4 + 3] = v;
    }
    for (int h = 1; h < 1024; h <<= 1) {
        __syncthreads();
        for (int w = tid; w < 512; w += 256) {
            int bh = w & (h - 1);
            int i  = ((w - bh) << 1) + bh;
            float a = s[i], c = s[i + h];
            s[i] = a + c; s[i + h] = a - c;
        }
    }
    __syncthreads();
    float4 v;
    v.x = s[tid * 4 + 0]; v.y = s[tid * 4 + 1]; v.z = s[tid * 4 + 2]; v.w = s[tid * 4 + 3];
    ((float4*)T)[row * 256 + tid] = v;
    if (tid == 0) partial[row] = ws4[0] + ws4[1] + ws4[2] + ws4[3];

    // ---- x f32 -> bf16 cast tail: this block's 3072-float4 slice ----
    const float4* X4 = (const float4*)X + (size_t)row * 3072;
    ushort4* XB4 = (ushort4*)XB + (size_t)row * 3072;
    #pragma unroll
    for (int j = 0; j < 12; j++) {
        float4 xv = X4[j * 256 + tid];
        ushort4 o;
        o.x = f2bf(xv.x); o.y = f2bf(xv.y); o.z = f2bf(xv.z); o.w = f2bf(xv.w);
        XB4[j * 256 + tid] = o;
    }
}

// ---------------------------------------------------------------------------
// K4: FWHT-1024 along the high-10 bits + W_eff epilogue.
// 128 blocks x 8 lo-columns each; LDS tile [8][1025] (pad -> conflict-free).
// Every block redundantly reduces the 1024 GG^2 partials (4 KB; no global S).
// Epilogue: WB[d] = bf16(W0[d] + v[d]*rsqrt(S*DD)) for d = hi*1024+lo < DD
// (hi < 768). T is never written back (k5 deleted).
// ---------------------------------------------------------------------------
__global__ void k4_fwht_hi(const float* __restrict__ T, const float* __restrict__ partial,
                           const float* __restrict__ W0, ushort* __restrict__ WB) {
    __shared__ float s[8 * 1025];
    __shared__ float rw[5];
    const int tid = threadIdx.x;
    // per-block S reduction (partials from k3)
    float p = partial[tid] + partial[tid + 256] + partial[tid + 512] + partial[tid + 768];
    #pragma unroll
    for (int o = 32; o > 0; o >>= 1) p += __shfl_down(p, o, 64);
    if ((tid & 63) == 0) rw[tid >> 6] = p;

    const int lo0 = blockIdx.x * 8;
    const float4* T4 = (const float4*)T;
    const int hio = tid >> 1;     // 0..127
    const int q   = tid & 1;      // which float4 of the 8 columns
    for (int hb = 0; hb < 8; hb++) {
        int hi = hb * 128 + hio;
        float4 v = T4[hi * 256 + (lo0 >> 2) + q];
        s[(4 * q + 0) * 1025 + hi] = v.x;
        s[(4 * q + 1) * 1025 + hi] = v.y;
        s[(4 * q + 2) * 1025 + hi] = v.z;
        s[(4 * q + 3) * 1025 + hi] = v.w;
    }
    __syncthreads();
    if (tid == 0) rw[4] = rw[0] + rw[1] + rw[2] + rw[3];
    for (int h = 1; h < 1024; h <<= 1) {
        for (int w = tid; w < 8 * 512; w += 256) {
            int col = w >> 9;
            int b   = w & 511;
            int bh  = b & (h - 1);
            int i   = ((b - bh) << 1) + bh;
            float* pp = s + col * 1025;
            float a = pp[i], c = pp[i + h];
            pp[i] = a + c; pp[i + h] = a - c;
        }
        __syncthreads();
    }
    const float scale = rsqrtf(rw[4] * (float)DD);
    // epilogue: only hi < 768 maps into W (d = hi*1024 + lo < DD)
    for (int hb = 0; hb < 6; hb++) {
        int hi = hb * 128 + hio;
        int d  = hi * 1024 + lo0 + 4 * q;      // 4-aligned
        float4 w = *(const float4*)&W0[d];
        ushort4 o;
        o.x = f2bf(w.x + s[(4 * q + 0) * 1025 + hi] * scale);
        o.y = f2bf(w.y + s[(4 * q + 1) * 1025 + hi] * scale);
        o.z = f2bf(w.z + s[(4 * q + 2) * 1025 + hi] * scale);
        o.w = f2bf(w.w + s[(4 * q + 3) * 1025 + hi] * scale);
        *(ushort4*)&WB[d] = o;
    }
}

// ---------------------------------------------------------------------------
// K7: GEMM  C[m][n] = sum_k A[m][k]*B[n][k] + bias[n]
// A: MROWS x 768 bf16, B: 1024 x 768 bf16 (W_eff), C: f32.
// 128x128 tile, BK=64, 4 waves (2x2), each wave 4x4 MFMA 16x16x32 x2 k-steps.
// XOR-swizzled LDS: 16B slot s <-> row = s>>3, kc = (s&7) ^ (row&7).
//   staging: lanes 8-at-a-time cover 128 B contiguous global memory;
//   fragment ds_read_b128: 2-way bank aliasing only (free per m136).
// Grid: x = m-tile (fast); all 8 n-blocks of one m-tile land on one XCD.
// ---------------------------------------------------------------------------
#define BM 128
#define BN 128
#define BK 64

__global__ __launch_bounds__(256)
void k7_gemm(const ushort* __restrict__ A, const ushort* __restrict__ B,
             const float* __restrict__ bias, float* __restrict__ C) {
    __shared__ ushort As[BM * BK];   // 16 KB
    __shared__ ushort Bs[BN * BK];   // 16 KB
    const int tid  = threadIdx.x;
    const int lane = tid & 63;
    const int wave = tid >> 6;
    const int m0 = blockIdx.x * BM;
    const int n0 = blockIdx.y * BN;
    const int wm = (wave & 1) * 64;
    const int wn = (wave >> 1) * 64;

    const int fr_row = lane & 15;
    const int fr_kg  = lane >> 4;     // k-group 0..3 (8 k each)

    f32x4 acc[4][4];
    #pragma unroll
    for (int i = 0; i < 4; i++)
        #pragma unroll
        for (int j = 0; j < 4; j++) acc[i][j] = (f32x4)(0.0f);

    for (int kt = 0; kt < INF; kt += BK) {
        // --- stage A/B tiles: 1024 slots x 16B each; XOR-swizzled mapping ---
        #pragma unroll
        for (int i = 0; i < 4; i++) {
            const int s   = i * 256 + tid;       // LDS slot (16B units)
            const int row = s >> 3;
            const int kc  = (s & 7) ^ (row & 7);
            const ushort* ga = A + (size_t)(m0 + row) * INF + kt + kc * 8;
            const ushort* gb = B + (size_t)(n0 + row) * INF + kt + kc * 8;
            __builtin_amdgcn_global_load_lds(
                (const __attribute__((address_space(1))) void*)ga,
                (__attribute__((address_space(3))) void*)&As[i * 2048 + wave * 512], 16, 0, 0);
            __builtin_amdgcn_global_load_lds(
                (const __attribute__((address_space(1))) void*)gb,
                (__attribute__((address_space(3))) void*)&Bs[i * 2048 + wave * 512], 16, 0, 0);
        }
        __syncthreads();

        // --- fragments + MFMA, two 32-k steps ---
        #pragma unroll
        for (int ks = 0; ks < 2; ks++) {
            const int kc = ks * 4 + fr_kg;
            s16x8 af[4], bf[4];
            #pragma unroll
            for (int mi = 0; mi < 4; mi++) {
                const int r = wm + mi * 16 + fr_row;
                af[mi] = *(const s16x8*)&As[(r * 8 + (kc ^ (r & 7))) * 8];
            }
            #pragma unroll
            for (int ni = 0; ni < 4; ni++) {
                const int r = wn + ni * 16 + fr_row;
                bf[ni] = *(const s16x8*)&Bs[(r * 8 + (kc ^ (r & 7))) * 8];
            }
            #pragma unroll
            for (int mi = 0; mi < 4; mi++)
                #pragma unroll
                for (int ni = 0; ni < 4; ni++)
                    acc[mi][ni] = __builtin_amdgcn_mfma_f32_16x16x32_bf16(
                        af[mi], bf[ni], acc[mi][ni], 0, 0, 0);
        }
        __syncthreads();
    }

    // --- epilogue: C/D layout col=lane&15, row=(lane>>4)*4+reg ---
    const int crow = (lane >> 4) * 4;
    const int ccol = lane & 15;
    #pragma unroll
    for (int ni = 0; ni < 4; ni++) {
        const int n = n0 + wn + ni * 16 + ccol;
        const float bv = bias[n];
        #pragma unroll
        for (int mi = 0; mi < 4; mi++) {
            const int mbase = m0 + wm + mi * 16 + crow;
            #pragma unroll
            for (int r = 0; r < 4; r++)
                C[(size_t)(mbase + r) * OUTF + n] = acc[mi][ni][r] + bv;
        }
    }
}

// ---------------------------------------------------------------------------
extern "C" void kernel_launch(void* const* d_in, const int* in_sizes, int n_in,
                              void* d_out, int out_size, void* d_ws, size_t ws_size,
                              hipStream_t stream) {
    (void)in_sizes; (void)n_in; (void)out_size; (void)ws_size;
    const float* x     = (const float*)d_in[0];
    const float* theta = (const float*)d_in[1];
    const float* W0    = (const float*)d_in[2];
    const float* bias  = (const float*)d_in[3];
    const float* BB    = (const float*)d_in[4];
    const float* GG    = (const float*)d_in[5];
    const int*   Pi    = (const int*)d_in[6];      // int64 inputs arrive as int32
    float* out = (float*)d_out;

    char* ws = (char*)d_ws;
    ushort* XB   = (ushort*)ws;                      // 16384*768 bf16 = 25165824 B
    float*  T    = (float*)(ws + 25165824);          // LL f32 = 4194304 B
    ushort* WB   = (ushort*)(ws + 29360128);         // 1024*768 bf16 = 1572864 B
    float*  PART = (float*)(ws + 30932992);          // 1024 f32 partials

    k3_gather_fwht_lo<<<1024, 256, 0, stream>>>(Pi, GG, BB, theta, x, XB, T, PART);
    k4_fwht_hi<<<128, 256, 0, stream>>>(T, PART, W0, WB);
    k7_gemm  <<<dim3(MROWS/BM, OUTF/BN), 256, 0, stream>>>(XB, WB, bias, out);
}

// Round 7
// 177.271 us; speedup vs baseline: 1.1913x; 1.0186x over previous
//
#include <hip/hip_runtime.h>
#include <hip/hip_bf16.h>

// ---------------------------------------------------------------------------
// GlobalIntrinsicLinear: Fastfood update + GEMM
//   LL = 1<<20, DD = 1024*768, OUT=1024, IN=768, M = 8*2048 = 16384
// Inputs: x(8,2048,768) f32, theta(2048) f32, W_0(1024,768) f32, b(1024) f32,
//         BB(LL) f32, GG(LL) f32, Pi(LL) int32 (harness narrows int64)
// Output: (8,2048,1024) f32
//
// R7: k7 switched to 32x32x16 MFMA (2x2 tiles/wave): per K-iter 16 ds_read +
//     16 MFMA vs 32+32 — halves the LDS-pipe load that R6's cycle model
//     showed as the limiter (1536 cyc LDS vs 614 MFMA per block-iter).
//     k3/k4 unchanged (R6 structure).
// ---------------------------------------------------------------------------

#define LL (1 << 20)
#define DD (1024 * 768)
#define OUTF 1024
#define INF 768
#define MROWS 16384

typedef __attribute__((ext_vector_type(8))) short s16x8;
typedef __attribute__((ext_vector_type(4))) float f32x4;
typedef __attribute__((ext_vector_type(16))) float f32x16;

__device__ __forceinline__ unsigned short f2bf(float f) {
    union { float f; unsigned u; } v; v.f = f;
    unsigned r = v.u + 0x7FFF + ((v.u >> 16) & 1);   // RNE
    return (unsigned short)(r >> 16);
}

// ---------------------------------------------------------------------------
// K3: fused {FWHT-1024 of the two nonzero rows of BB*theta_pad} + gather +
// FWHT-1024 along low-10 bits + sum(GG^2) block partials + x-cast tail.
// One hi-row per block (1024 blocks).
// Math: FWHT_{2^20} of a vector nonzero only at q<2048 collapses to
//   v1[p] = r0[p&1023] + (-1)^{bit10(p)} * r1[p&1023],  r0/r1 = FWHT_1024 rows.
// ---------------------------------------------------------------------------
__global__ void k3_gather_fwht_lo(const int* __restrict__ Pi, const float* __restrict__ GG,
                                  const float* __restrict__ BB, const float* __restrict__ theta,
                                  const float* __restrict__ X, ushort* __restrict__ XB,
                                  float* __restrict__ T, float* __restrict__ partial) {
    __shared__ float s[1024];
    __shared__ float r01s[2048];
    __shared__ float ws4[4];
    const int tid = threadIdx.x;
    const int row = blockIdx.x;
    // gather operands early (latency hidden behind r01 butterflies)
    const int4   pv = ((const int4*)Pi)[row * 256 + tid];
    const float4 gv = ((const float4*)GG)[row * 256 + tid];
    for (int j = tid; j < 2048; j += 256) r01s[j] = BB[j] * theta[j];
    for (int h = 1; h < 1024; h <<= 1) {
        __syncthreads();
        for (int w = tid; w < 1024; w += 256) {
            int rr = w >> 9;
            int b  = w & 511;
            int bh = b & (h - 1);
            int i  = ((b - bh) << 1) + bh + rr * 1024;
            float a = r01s[i], c = r01s[i + h];
            r01s[i] = a + c; r01s[i + h] = a - c;
        }
    }
    // sum(GG^2) partial for this block (no atomics)
    float g2 = gv.x * gv.x + gv.y * gv.y + gv.z * gv.z + gv.w * gv.w;
    #pragma unroll
    for (int o = 32; o > 0; o >>= 1) g2 += __shfl_down(g2, o, 64);
    if ((tid & 63) == 0) ws4[tid >> 6] = g2;
    __syncthreads();
    {
        int p; float g, v;
        p = pv.x; g = gv.x;
        v = (r01s[p & 1023] + (((p >> 10) & 1) ? -1.0f : 1.0f) * r01s[1024 + (p & 1023)]) * g;
        s[tid * 4 + 0] = v;
        p = pv.y; g = gv.y;
        v = (r01s[p & 1023] + (((p >> 10) & 1) ? -1.0f : 1.0f) * r01s[1024 + (p & 1023)]) * g;
        s[tid * 4 + 1] = v;
        p = pv.z; g = gv.z;
        v = (r01s[p & 1023] + (((p >> 10) & 1) ? -1.0f : 1.0f) * r01s[1024 + (p & 1023)]) * g;
        s[tid * 4 + 2] = v;
        p = pv.w; g = gv.w;
        v = (r01s[p & 1023] + (((p >> 10) & 1) ? -1.0f : 1.0f) * r01s[1024 + (p & 1023)]) * g;
        s[tid * 4 + 3] = v;
    }
    for (int h = 1; h < 1024; h <<= 1) {
        __syncthreads();
        for (int w = tid; w < 512; w += 256) {
            int bh = w & (h - 1);
            int i  = ((w - bh) << 1) + bh;
            float a = s[i], c = s[i + h];
            s[i] = a + c; s[i + h] = a - c;
        }
    }
    __syncthreads();
    float4 v;
    v.x = s[tid * 4 + 0]; v.y = s[tid * 4 + 1]; v.z = s[tid * 4 + 2]; v.w = s[tid * 4 + 3];
    ((float4*)T)[row * 256 + tid] = v;
    if (tid == 0) partial[row] = ws4[0] + ws4[1] + ws4[2] + ws4[3];

    // ---- x f32 -> bf16 cast tail: this block's 3072-float4 slice ----
    const float4* X4 = (const float4*)X + (size_t)row * 3072;
    ushort4* XB4 = (ushort4*)XB + (size_t)row * 3072;
    #pragma unroll
    for (int j = 0; j < 12; j++) {
        float4 xv = X4[j * 256 + tid];
        ushort4 o;
        o.x = f2bf(xv.x); o.y = f2bf(xv.y); o.z = f2bf(xv.z); o.w = f2bf(xv.w);
        XB4[j * 256 + tid] = o;
    }
}

// ---------------------------------------------------------------------------
// K4: FWHT-1024 along the high-10 bits + W_eff epilogue.
// 128 blocks x 8 lo-columns each; LDS tile [8][1025] (pad -> conflict-free).
// Every block redundantly reduces the 1024 GG^2 partials (4 KB; no global S).
// Epilogue: WB[d] = bf16(W0[d] + v[d]*rsqrt(S*DD)) for d = hi*1024+lo < DD.
// ---------------------------------------------------------------------------
__global__ void k4_fwht_hi(const float* __restrict__ T, const float* __restrict__ partial,
                           const float* __restrict__ W0, ushort* __restrict__ WB) {
    __shared__ float s[8 * 1025];
    __shared__ float rw[5];
    const int tid = threadIdx.x;
    // per-block S reduction (partials from k3)
    float p = partial[tid] + partial[tid + 256] + partial[tid + 512] + partial[tid + 768];
    #pragma unroll
    for (int o = 32; o > 0; o >>= 1) p += __shfl_down(p, o, 64);
    if ((tid & 63) == 0) rw[tid >> 6] = p;

    const int lo0 = blockIdx.x * 8;
    const float4* T4 = (const float4*)T;
    const int hio = tid >> 1;     // 0..127
    const int q   = tid & 1;      // which float4 of the 8 columns
    for (int hb = 0; hb < 8; hb++) {
        int hi = hb * 128 + hio;
        float4 v = T4[hi * 256 + (lo0 >> 2) + q];
        s[(4 * q + 0) * 1025 + hi] = v.x;
        s[(4 * q + 1) * 1025 + hi] = v.y;
        s[(4 * q + 2) * 1025 + hi] = v.z;
        s[(4 * q + 3) * 1025 + hi] = v.w;
    }
    __syncthreads();
    if (tid == 0) rw[4] = rw[0] + rw[1] + rw[2] + rw[3];
    for (int h = 1; h < 1024; h <<= 1) {
        for (int w = tid; w < 8 * 512; w += 256) {
            int col = w >> 9;
            int b   = w & 511;
            int bh  = b & (h - 1);
            int i   = ((b - bh) << 1) + bh;
            float* pp = s + col * 1025;
            float a = pp[i], c = pp[i + h];
            pp[i] = a + c; pp[i + h] = a - c;
        }
        __syncthreads();
    }
    const float scale = rsqrtf(rw[4] * (float)DD);
    // epilogue: only hi < 768 maps into W (d = hi*1024 + lo < DD)
    for (int hb = 0; hb < 6; hb++) {
        int hi = hb * 128 + hio;
        int d  = hi * 1024 + lo0 + 4 * q;      // 4-aligned
        float4 w = *(const float4*)&W0[d];
        ushort4 o;
        o.x = f2bf(w.x + s[(4 * q + 0) * 1025 + hi] * scale);
        o.y = f2bf(w.y + s[(4 * q + 1) * 1025 + hi] * scale);
        o.z = f2bf(w.z + s[(4 * q + 2) * 1025 + hi] * scale);
        o.w = f2bf(w.w + s[(4 * q + 3) * 1025 + hi] * scale);
        *(ushort4*)&WB[d] = o;
    }
}

// ---------------------------------------------------------------------------
// K7: GEMM  C[m][n] = sum_k A[m][k]*B[n][k] + bias[n]
// A: MROWS x 768 bf16, B: 1024 x 768 bf16 (W_eff), C: f32.
// 128x128 tile, BK=64, 4 waves (2x2), each wave 2x2 MFMA 32x32x16 tiles
// x4 k-steps (K=16 each). 16 ds_read_b128 + 16 MFMA per K-iter (was 32+32).
// XOR-swizzled LDS: 16B slot s <-> row = s>>3, kc = (s&7) ^ (row&7).
// A-frag: m = lane&31, k = (lane>>5)*8 + j  (symmetric ext of 16x16x32).
// C/D: col = lane&31, row = (reg&3) + 8*(reg>>2) + 4*(lane>>5)  [m74/m101].
// ---------------------------------------------------------------------------
#define BM 128
#define BN 128
#define BK 64

__global__ __launch_bounds__(256)
void k7_gemm(const ushort* __restrict__ A, const ushort* __restrict__ B,
             const float* __restrict__ bias, float* __restrict__ C) {
    __shared__ ushort As[BM * BK];   // 16 KB
    __shared__ ushort Bs[BN * BK];   // 16 KB
    const int tid  = threadIdx.x;
    const int lane = tid & 63;
    const int wave = tid >> 6;
    const int m0 = blockIdx.x * BM;
    const int n0 = blockIdx.y * BN;
    const int wm = (wave & 1) * 64;
    const int wn = (wave >> 1) * 64;

    const int fr_row = lane & 31;     // row within 32-tile
    const int fr_kh  = lane >> 5;     // k-half 0..1 (8 k each)

    f32x16 acc[2][2];
    #pragma unroll
    for (int i = 0; i < 2; i++)
        #pragma unroll
        for (int j = 0; j < 2; j++) acc[i][j] = (f32x16)(0.0f);

    for (int kt = 0; kt < INF; kt += BK) {
        // --- stage A/B tiles: 1024 slots x 16B each; XOR-swizzled mapping ---
        #pragma unroll
        for (int i = 0; i < 4; i++) {
            const int s   = i * 256 + tid;       // LDS slot (16B units)
            const int row = s >> 3;
            const int kc  = (s & 7) ^ (row & 7);
            const ushort* ga = A + (size_t)(m0 + row) * INF + kt + kc * 8;
            const ushort* gb = B + (size_t)(n0 + row) * INF + kt + kc * 8;
            __builtin_amdgcn_global_load_lds(
                (const __attribute__((address_space(1))) void*)ga,
                (__attribute__((address_space(3))) void*)&As[i * 2048 + wave * 512], 16, 0, 0);
            __builtin_amdgcn_global_load_lds(
                (const __attribute__((address_space(1))) void*)gb,
                (__attribute__((address_space(3))) void*)&Bs[i * 2048 + wave * 512], 16, 0, 0);
        }
        __syncthreads();

        // --- fragments + MFMA, four 16-k steps ---
        #pragma unroll
        for (int ks = 0; ks < 4; ks++) {
            const int kc = ks * 2 + fr_kh;       // 8-ushort unit within BK
            s16x8 af[2], bf[2];
            #pragma unroll
            for (int mi = 0; mi < 2; mi++) {
                const int r = wm + mi * 32 + fr_row;
                af[mi] = *(const s16x8*)&As[(r * 8 + (kc ^ (r & 7))) * 8];
            }
            #pragma unroll
            for (int ni = 0; ni < 2; ni++) {
                const int r = wn + ni * 32 + fr_row;
                bf[ni] = *(const s16x8*)&Bs[(r * 8 + (kc ^ (r & 7))) * 8];
            }
            #pragma unroll
            for (int mi = 0; mi < 2; mi++)
                #pragma unroll
                for (int ni = 0; ni < 2; ni++)
                    acc[mi][ni] = __builtin_amdgcn_mfma_f32_32x32x16_bf16(
                        af[mi], bf[ni], acc[mi][ni], 0, 0, 0);
        }
        __syncthreads();
    }

    // --- epilogue: C/D col=lane&31, row=(reg&3)+8*(reg>>2)+4*(lane>>5) ---
    const int ccol = lane & 31;
    const int rbase = (lane >> 5) * 4;
    #pragma unroll
    for (int ni = 0; ni < 2; ni++) {
        const int n = n0 + wn + ni * 32 + ccol;
        const float bv = bias[n];
        #pragma unroll
        for (int mi = 0; mi < 2; mi++) {
            const int mb = m0 + wm + mi * 32 + rbase;
            #pragma unroll
            for (int r = 0; r < 16; r++) {
                const int m = mb + (r & 3) + 8 * (r >> 2);
                C[(size_t)m * OUTF + n] = acc[mi][ni][r] + bv;
            }
        }
    }
}

// ---------------------------------------------------------------------------
extern "C" void kernel_launch(void* const* d_in, const int* in_sizes, int n_in,
                              void* d_out, int out_size, void* d_ws, size_t ws_size,
                              hipStream_t stream) {
    (void)in_sizes; (void)n_in; (void)out_size; (void)ws_size;
    const float* x     = (const float*)d_in[0];
    const float* theta = (const float*)d_in[1];
    const float* W0    = (const float*)d_in[2];
    const float* bias  = (const float*)d_in[3];
    const float* BB    = (const float*)d_in[4];
    const float* GG    = (const float*)d_in[5];
    const int*   Pi    = (const int*)d_in[6];      // int64 inputs arrive as int32
    float* out = (float*)d_out;

    char* ws = (char*)d_ws;
    ushort* XB   = (ushort*)ws;                      // 16384*768 bf16 = 25165824 B
    float*  T    = (float*)(ws + 25165824);          // LL f32 = 4194304 B
    ushort* WB   = (ushort*)(ws + 29360128);         // 1024*768 bf16 = 1572864 B
    float*  PART = (float*)(ws + 30932992);          // 1024 f32 partials

    k3_gather_fwht_lo<<<1024, 256, 0, stream>>>(Pi, GG, BB, theta, x, XB, T, PART);
    k4_fwht_hi<<<128, 256, 0, stream>>>(T, PART, W0, WB);
    k7_gemm  <<<dim3(MROWS/BM, OUTF/BN), 256, 0, stream>>>(XB, WB, bias, out);
}